// Round 6
// baseline (160.277 us; speedup 1.0000x reference)
//
#include <hip/hip_runtime.h>
#include <math.h>

#define NB 32
#define DM 128
#define SL 2048
#define WIN 64
#define NT  (SL / 16)    // 128 j-tiles of 16
#define PADF 4           // front pad tiles (j in [-64,0))
#define PADB 6           // back pad tiles  (j in [SL, SL+96))
#define NTP (NT + PADF + PADB)   // 138 tiles per (n)
#define YST 132          // ylds row stride (floats)
#define OST 68           // ot row stride (floats, 16B-aligned rows, 2-way banks)
#define NSEG 64          // qkv l-blocks per n (SL/32)

typedef __attribute__((ext_vector_type(8))) short bf16x8;
typedef __attribute__((ext_vector_type(8))) unsigned short u16x8;
typedef __attribute__((ext_vector_type(4))) float f32x4;

__device__ inline ushort bf16_rne(float f) {
    union { float f; unsigned u; } v; v.f = f;
    unsigned u = v.u;
    return (ushort)((u + 0x7FFFu + ((u >> 16) & 1u)) >> 16);
}
__device__ inline float bf16_to_f(ushort h) {
    union { unsigned u; float f; } v; v.u = ((unsigned)h) << 16;
    return v.f;
}
// hi = truncated top bits (1 op); lo = rne(residual) absorbs the trunc error.
__device__ inline ushort bf16_hi_trunc(float f) {
    union { float f; unsigned u; } v; v.f = f;
    return (ushort)(v.u >> 16);
}

// ---------------------------------------------------------------------------
// ws layout:
//   sqT   : NB*NT*2048 ushort sigmoid(q) as unorm16, TILED [n][jt][d][jo]
//                             (same tile structure as ekTF; no pad tiles)
//   ekTF  : NB*NTP*2048 bf16  exp(k) in 16-j x 128-d tiles [n][jt][d][jo],
//                             jt offset by PADF; pad tiles zeroed by qkv bx<10
//   ekvTF : same              exp(k)*v
//   WB    : 128*2560 bf16     banded weights, A-frag order per 16-i tile
//   Pk/Pkv: NB*NSEG*DM fp32   per-block partial sums (reduced inside band_out)
//   Wh/Wl : 4*128*128 bf16    split W (Wq,Wk,Wv,Wo), B-frag order
// ---------------------------------------------------------------------------

// Setup: blocks 0..127 pack W (B-frag, split hi/lo); 128..383 build WB.
__global__ __launch_bounds__(512) void setup_kernel(
    const float* __restrict__ Wq, const float* __restrict__ Wk,
    const float* __restrict__ Wv, const float* __restrict__ Wo,
    const float* __restrict__ pos_bias,
    ushort* __restrict__ Wh, ushort* __restrict__ Wl,
    ushort* __restrict__ WB)
{
    const int b = blockIdx.x;
    const int tid = threadIdx.x;
    if (b < 128) {
        // ---- pack Wq/Wk/Wv/Wo into B-frag order, split hi/lo bf16 ----
        const int id = b;                 // (mat*8+ct)*4+ks
        const int mat = id >> 5;
        const int ct = (id & 31) >> 2, ks = id & 3;
        const int lane = tid >> 3, j = tid & 7;
        const int k = ks * 32 + (lane >> 4) * 8 + j;
        const int col = ct * 16 + (lane & 15);
        const float* W = (mat == 0) ? Wq : ((mat == 1) ? Wk : ((mat == 2) ? Wv : Wo));
        float w = W[k * DM + col];
        ushort h = bf16_rne(w);
        Wh[(size_t)id * 512 + tid] = h;
        Wl[(size_t)id * 512 + tid] = bf16_rne(w - bf16_to_f(h));
    } else {
        // ---- banded weights in A-frag order per 16-i tile, 2 blocks/tile ----
        const int idx = b - 128;          // 0..255
        const int it = idx >> 1;          // 0..127
        const int half = idx & 1;
        const int i0 = it * 16;
        const int tend = half * 1280 + 1280;
        for (int t = half * 1280 + tid; t < tend; t += 512) {
            const int ks = t >> 9;
            const int lane = (t >> 3) & 63;
            const int jj = t & 7;
            const int m = lane & 15;
            const int k = ks * 32 + ((lane >> 4) << 3) + jj;
            const int i = i0 + m;
            const int j = i0 - 64 + k;
            const int rel = k - 64 - m;  // j - i
            float val = 0.f;
            if (rel > -WIN && rel < WIN && j >= 0 && j < SL)
                val = __expf(pos_bias[(size_t)i * SL + j]) - 1.f;
            WB[(size_t)it * 2560 + t] = bf16_rne(val);
        }
    }
}

// QKV projection via split-bf16 MFMA.
// Block = (n, 32 l's), 512 threads / 8 waves; wave w owns dt slice w (16 d's)
// for all 3 matrices, 2 l-tiles. Epilogue stores are ALL ushort4 tiled now
// (sq moved to the same [n][jt][d][jo] tiling as ekTF).
__global__ __launch_bounds__(512, 6) void qkv_kernel(
    const float* __restrict__ x,
    const ushort* __restrict__ Wh, const ushort* __restrict__ Wl,
    const float* __restrict__ bq, const float* __restrict__ bk,
    const float* __restrict__ bv,
    ushort* __restrict__ sqT, ushort* __restrict__ ekTF, ushort* __restrict__ ekvTF,
    float* __restrict__ Pk, float* __restrict__ Pkv)
{
    __shared__ ushort Ah[32 * 128];   // frag order: ((lt*4+ks)*64+lane)*8+j
    __shared__ ushort Al[32 * 128];
    const int n = blockIdx.y, bx = blockIdx.x, l0 = bx * 32;
    const int tid = threadIdx.x;
    const int wave = tid >> 6;        // = dt slice 0..7
    const int lane = tid & 63;

    // Pad-tile zeroing (front 4 + back 6 tiles per n), done by blocks bx<10.
    if (bx < 10) {
        const int jt_p = (bx < PADF) ? bx : (NT + bx);   // 0..3, 132..137
        const size_t zb = ((size_t)n * NTP + jt_p) * 2048 + (size_t)tid * 4;
        ushort4 z; z.x = 0; z.y = 0; z.z = 0; z.w = 0;
        *(ushort4*)&ekTF [zb] = z;
        *(ushort4*)&ekvTF[zb] = z;
    }

    // ---- stage x tile (32 l x 128 c) into A-frag order, split hi/lo ----
    {
        const int lo = tid & 31;          // l within tile
        const int cq = tid >> 5;          // 0..15, c0 = cq*8
        const int l  = l0 + lo;
        const int c0 = cq * 8;
        float xv[8];
        #pragma unroll
        for (int u = 0; u < 8; ++u)
            xv[u] = x[((size_t)n * DM + c0 + u) * SL + l];
        u16x8 hv, lv;
        #pragma unroll
        for (int u = 0; u < 8; ++u) {
            const ushort h = bf16_hi_trunc(xv[u]);
            hv[u] = h;
            lv[u] = bf16_rne(xv[u] - bf16_to_f(h));
        }
        const int lt = lo >> 4, m = lo & 15;
        const int ks = cq >> 2, oct = cq & 3;
        const int idx = ((lt * 4 + ks) * 64 + oct * 16 + m) * 8;
        *(u16x8*)&Ah[idx] = hv;
        *(u16x8*)&Al[idx] = lv;
    }
    __syncthreads();

    const int dcol = lane & 15;
    const int d = wave * 16 + dcol;

    f32x4 acc[3][2];
    {
        const float b0 = bq[d], b1 = bk[d], b2 = bv[d];
        #pragma unroll
        for (int lt = 0; lt < 2; ++lt) {
            acc[0][lt] = (f32x4){b0, b0, b0, b0};
            acc[1][lt] = (f32x4){b1, b1, b1, b1};
            acc[2][lt] = (f32x4){b2, b2, b2, b2};
        }
    }

    const bf16x8* WhV = (const bf16x8*)Wh;
    const bf16x8* WlV = (const bf16x8*)Wl;
    #pragma unroll
    for (int ks = 0; ks < 4; ++ks) {
        bf16x8 bh[3], bl[3];
        #pragma unroll
        for (int m = 0; m < 3; ++m) {
            const int fi = ((m * 8 + wave) * 4 + ks) * 64 + lane;
            bh[m] = WhV[fi];
            bl[m] = WlV[fi];
        }
        #pragma unroll
        for (int lt = 0; lt < 2; ++lt) {
            const bf16x8 ah = *(const bf16x8*)&Ah[((lt * 4 + ks) * 64 + lane) * 8];
            const bf16x8 al = *(const bf16x8*)&Al[((lt * 4 + ks) * 64 + lane) * 8];
            #pragma unroll
            for (int m = 0; m < 3; ++m) {
                acc[m][lt] = __builtin_amdgcn_mfma_f32_16x16x32_bf16(
                    ah, bh[m], acc[m][lt], 0, 0, 0);
                acc[m][lt] = __builtin_amdgcn_mfma_f32_16x16x32_bf16(
                    al, bh[m], acc[m][lt], 0, 0, 0);
                acc[m][lt] = __builtin_amdgcn_mfma_f32_16x16x32_bf16(
                    ah, bl[m], acc[m][lt], 0, 0, 0);
            }
        }
    }

    const int lrow0 = (lane >> 4) * 4;
    float psk = 0.f, pskv = 0.f;
    #pragma unroll
    for (int lt = 0; lt < 2; ++lt) {
        const f32x4 q4 = acc[0][lt];
        const f32x4 k4 = acc[1][lt];
        const f32x4 v4 = acc[2][lt];
        ushort eh[4], zh[4], sh[4];
        #pragma unroll
        for (int r = 0; r < 4; ++r) {
            const float e = __expf(k4[r]);
            const float z = e * v4[r];
            const float s = fminf(__builtin_amdgcn_rcpf(1.f + __expf(-q4[r])), 1.f);
            sh[r] = (ushort)(s * 65535.f + 0.5f);
            eh[r] = bf16_rne(e);
            zh[r] = bf16_rne(z);
            psk  += e;
            pskv += z;
        }
        // tiled stores: tile jt = bx*2 + lt, row d, jo = lrow0..lrow0+3
        const int jt = bx * 2 + lt;
        const size_t tb = ((size_t)n * NTP + PADF + jt) * 2048
                        + (size_t)d * 16 + lrow0;
        const size_t sb = ((size_t)n * NT + jt) * 2048
                        + (size_t)d * 16 + lrow0;
        ushort4 ev; ev.x = eh[0]; ev.y = eh[1]; ev.z = eh[2]; ev.w = eh[3];
        ushort4 zv; zv.x = zh[0]; zv.y = zh[1]; zv.z = zh[2]; zv.w = zh[3];
        ushort4 sv; sv.x = sh[0]; sv.y = sh[1]; sv.z = sh[2]; sv.w = sh[3];
        *(ushort4*)&ekTF [tb] = ev;
        *(ushort4*)&ekvTF[tb] = zv;
        *(ushort4*)&sqT  [sb] = sv;
    }
    {
        float a = psk, b = pskv;
        a += __shfl_xor(a, 16, 64); a += __shfl_xor(a, 32, 64);
        b += __shfl_xor(b, 16, 64); b += __shfl_xor(b, 32, 64);
        if (lane < 16) {
            const size_t o = ((size_t)n * NSEG + bx) * DM + d;
            Pk [o] = a;
            Pkv[o] = b;
        }
    }
}

// FUSED band correction + output projection, wave-local handoff.
// Gate reads sqT in tiled ushort4 form; out drained with float4 stores.
__global__ __launch_bounds__(256, 4) void band_out_kernel(
    const ushort* __restrict__ ekTF, const ushort* __restrict__ ekvTF,
    const ushort* __restrict__ WB,
    const float* __restrict__ Pk, const float* __restrict__ Pkv,
    const ushort* __restrict__ sqT,
    const ushort* __restrict__ Wh, const ushort* __restrict__ Wl,
    const float* __restrict__ bo, float* __restrict__ out)
{
    __shared__ __align__(16) union {
        float ylds[64 * YST];   // y fp32, [row l_local][col d]
        float ot[128 * OST];    // out transpose buffer [c][l_local]
    } u;
    __shared__ float SkL[DM], SkvL[DM];

    const int bid = blockIdx.x;          // 0..1023
    const int xcd = bid & 7;
    const int slot = bid >> 3;           // 0..127
    const int nsub = slot >> 5;          // 0..3
    const int itg  = slot & 31;          // 0..31
    const int n = xcd * 4 + nsub;        // 4 n's per XCD
    const int wave = threadIdx.x >> 6;
    const int lane = threadIdx.x & 63;
    const int it = itg * 4 + wave;       // 0..127
    const int l0 = itg * 64;

    const int dcol = lane & 15;
    const int jgrp8 = (lane >> 4) << 3;

    // Hoist all 5 WB A-fragments (hides L2 latency under the Pk reduction).
    const bf16x8* WBv = (const bf16x8*)(WB + (size_t)it * 2560);
    bf16x8 aWB[5];
    #pragma unroll
    for (int ks = 0; ks < 5; ++ks) aWB[ks] = WBv[ks * 64 + lane];

    // ---- Reduce Pk/Pkv -> SkL/SkvL (threads 0-127: Sk, 128-255: Skv) ----
    {
        const int tdd = threadIdx.x & 127;
        const float* P = (threadIdx.x < 128) ? Pk : Pkv;
        float s = 0.f;
        #pragma unroll
        for (int seg = 0; seg < NSEG; ++seg)
            s += P[((size_t)n * NSEG + seg) * DM + tdd];
        if (threadIdx.x < 128) SkL[tdd] = s; else SkvL[tdd] = s;
    }
    __syncthreads();

    // ---- Phase 1: banded MFMA over tiled layout ----
    f32x4 den[8], num[8];
    #pragma unroll
    for (int dt = 0; dt < 8; ++dt) {
        const float sk = SkL [dt * 16 + dcol];
        const float sv = SkvL[dt * 16 + dcol];
        den[dt] = (f32x4){sk, sk, sk, sk};
        num[dt] = (f32x4){sv, sv, sv, sv};
    }

    // lane-dependent tile select: jt_p = it + 2ks + (lane>>5); jo = ((lane>>4)&1)*8
    const size_t lsel = (size_t)(lane >> 5) * 2048 + (size_t)((lane >> 4) & 1) * 8
                      + (size_t)dcol * 16;
    #pragma unroll
    for (int ks = 0; ks < 5; ++ks) {
        const bf16x8 a = aWB[ks];
        const size_t tb = ((size_t)n * NTP + it + 2 * ks) * 2048 + lsel;
        #pragma unroll
        for (int dt = 0; dt < 8; ++dt) {
            const size_t rbase = tb + (size_t)dt * 256;   // dt*16 rows * 16 jo
            const bf16x8 bden = *(const bf16x8*)(ekTF  + rbase);
            const bf16x8 bnum = *(const bf16x8*)(ekvTF + rbase);
            den[dt] = __builtin_amdgcn_mfma_f32_16x16x32_bf16(a, bden, den[dt], 0, 0, 0);
            num[dt] = __builtin_amdgcn_mfma_f32_16x16x32_bf16(a, bnum, num[dt], 0, 0, 0);
        }
    }

    // Gate with sigmoid(q) (unorm16, tiled ushort4 reads); write y to LDS stripe.
    const int irow0 = (lane >> 4) << 2;
    const size_t sgb = ((size_t)n * NT + it) * 2048 + irow0;
    #pragma unroll
    for (int dt = 0; dt < 8; ++dt) {
        const int d = dt * 16 + dcol;
        const ushort4 s4 = *(const ushort4*)&sqT[sgb + (size_t)d * 16];
        float sf[4];
        sf[0] = (float)s4.x; sf[1] = (float)s4.y;
        sf[2] = (float)s4.z; sf[3] = (float)s4.w;
        #pragma unroll
        for (int r = 0; r < 4; ++r) {
            const float s = sf[r] * (1.f / 65535.f);
            const float y = s * num[dt][r] * __builtin_amdgcn_rcpf(den[dt][r]);
            u.ylds[(wave * 16 + irow0 + r) * YST + d] = y;
        }
    }

    // ---- Handoff: read own stripe in A-octet order, convert immediately ----
    bf16x8 yh[4], yl[4];
    {
        const int arow = wave * 16 + (lane & 15);
        #pragma unroll
        for (int ks = 0; ks < 4; ++ks) {
            const int base = arow * YST + ks * 32 + jgrp8;
            const float4 a0 = *(const float4*)&u.ylds[base];
            const float4 a1 = *(const float4*)&u.ylds[base + 4];
            float af[8];
            af[0] = a0.x; af[1] = a0.y; af[2] = a0.z; af[3] = a0.w;
            af[4] = a1.x; af[5] = a1.y; af[6] = a1.z; af[7] = a1.w;
            #pragma unroll
            for (int t = 0; t < 8; ++t) {
                const ushort h = bf16_hi_trunc(af[t]);
                yh[ks][t] = (short)h;
                yl[ks][t] = (short)bf16_rne(af[t] - bf16_to_f(h));
            }
        }
    }
    __syncthreads();   // all waves done with ylds; ot may now overwrite

    // ---- Phase 2: out projection, own 16 rows x all 128 c ----
    f32x4 acc[8];
    #pragma unroll
    for (int ct = 0; ct < 8; ++ct) {
        const float b0 = bo[ct * 16 + dcol];
        acc[ct] = (f32x4){b0, b0, b0, b0};
    }

    const bf16x8* WhV = (const bf16x8*)Wh;
    const bf16x8* WlV = (const bf16x8*)Wl;
    #pragma unroll
    for (int ks = 0; ks < 4; ++ks) {
        #pragma unroll
        for (int ct = 0; ct < 8; ++ct) {
            const int fi = ((24 + ct) * 4 + ks) * 64 + lane;  // mat=3 (Wo)
            const bf16x8 bh = WhV[fi];
            const bf16x8 bl = WlV[fi];
            acc[ct] = __builtin_amdgcn_mfma_f32_16x16x32_bf16(yh[ks], bh, acc[ct], 0, 0, 0);
            acc[ct] = __builtin_amdgcn_mfma_f32_16x16x32_bf16(yl[ks], bh, acc[ct], 0, 0, 0);
            acc[ct] = __builtin_amdgcn_mfma_f32_16x16x32_bf16(yh[ks], bl, acc[ct], 0, 0, 0);
        }
    }

    // Transpose through LDS: ot[c][l_local]; C rows = wave's 16 l's.
    #pragma unroll
    for (int ct = 0; ct < 8; ++ct) {
        const int c = ct * 16 + dcol;
        #pragma unroll
        for (int r = 0; r < 4; ++r)
            u.ot[c * OST + wave * 16 + irow0 + r] = acc[ct][r];
    }
    __syncthreads();

    // Coalesced float4 store: 64 contiguous floats per c row, 8 reps.
    const int tid = threadIdx.x;
    #pragma unroll
    for (int rep = 0; rep < 8; ++rep) {
        const int e = rep * 256 + tid;   // 0..2047
        const int c = e >> 4;            // 0..127
        const int lq = e & 15;           // 0..15 -> 4-float chunk
        const float4 v = *(const float4*)&u.ot[c * OST + lq * 4];
        *(float4*)&out[((size_t)n * DM + c) * SL + l0 + lq * 4] = v;
    }
}

extern "C" void kernel_launch(void* const* d_in, const int* in_sizes, int n_in,
                              void* d_out, int out_size, void* d_ws, size_t ws_size,
                              hipStream_t stream)
{
    const float* x        = (const float*)d_in[0];
    const float* Wq       = (const float*)d_in[1];
    const float* bq       = (const float*)d_in[2];
    const float* Wk       = (const float*)d_in[3];
    const float* bk       = (const float*)d_in[4];
    const float* Wv       = (const float*)d_in[5];
    const float* bv       = (const float*)d_in[6];
    const float* Wo       = (const float*)d_in[7];
    const float* bo       = (const float*)d_in[8];
    const float* pos_bias = (const float*)d_in[9];
    float* out = (float*)d_out;

    ushort* sqT   = (ushort*)d_ws;                       // NB*NT*2048 ushorts
    ushort* ekTF  = sqT   + (size_t)NB * NT * 2048;
    ushort* ekvTF = ekTF  + (size_t)NB * NTP * 2048;
    ushort* WB    = ekvTF + (size_t)NB * NTP * 2048;
    float*  Pk    = (float*)(WB + (size_t)128 * 2560);
    float*  Pkv   = Pk   + (size_t)NB * NSEG * DM;
    ushort* Wh    = (ushort*)(Pkv + (size_t)NB * NSEG * DM);
    ushort* Wl    = Wh + (size_t)4 * DM * DM;

    setup_kernel   <<<dim3(384),      512, 0, stream>>>(Wq, Wk, Wv, Wo, pos_bias,
                                                        Wh, Wl, WB);
    qkv_kernel     <<<dim3(NSEG, NB), 512, 0, stream>>>(x, Wh, Wl, bq, bk, bv,
                                                        sqT, ekTF, ekvTF, Pk, Pkv);
    band_out_kernel<<<dim3(NB * 32),  256, 0, stream>>>(ekTF, ekvTF, WB, Pk, Pkv, sqT,
                                                        Wh, Wl, bo, out);
}

// Round 7
// 159.386 us; speedup vs baseline: 1.0056x; 1.0056x over previous
//
#include <hip/hip_runtime.h>
#include <math.h>

#define NB 32
#define DM 128
#define SL 2048
#define WIN 64
#define NT  (SL / 16)    // 128 j-tiles of 16
#define PADF 4           // front pad tiles (j in [-64,0))
#define PADB 6           // back pad tiles  (j in [SL, SL+96))
#define NTP (NT + PADF + PADB)   // 138 tiles per (n)
#define YST 132          // ylds row stride (floats)
#define OST 68           // ot row stride (floats, 16B-aligned rows, 2-way banks)
#define NSEG 64          // qkv l-blocks per n (SL/32)

typedef __attribute__((ext_vector_type(8))) short bf16x8;
typedef __attribute__((ext_vector_type(8))) unsigned short u16x8;
typedef __attribute__((ext_vector_type(4))) float f32x4;

__device__ inline ushort bf16_rne(float f) {
    union { float f; unsigned u; } v; v.f = f;
    unsigned u = v.u;
    return (ushort)((u + 0x7FFFu + ((u >> 16) & 1u)) >> 16);
}
__device__ inline float bf16_to_f(ushort h) {
    union { unsigned u; float f; } v; v.u = ((unsigned)h) << 16;
    return v.f;
}
// hi = truncated top bits (1 op); lo = rne(residual) absorbs the trunc error.
__device__ inline ushort bf16_hi_trunc(float f) {
    union { float f; unsigned u; } v; v.f = f;
    return (ushort)(v.u >> 16);
}

// ---------------------------------------------------------------------------
// ws layout:
//   sqT   : NB*NT*2048 ushort sigmoid(q) as unorm16, TILED [n][jt][d][jo]
//   ekTF  : NB*NTP*2048 bf16  exp(k) in 16-j x 128-d tiles [n][jt][d][jo],
//                             jt offset by PADF; pad tiles zeroed by qkv bx<10
//   ekvTF : same              exp(k)*v
//   WB    : 128*2560 bf16     banded weights, A-frag order per 16-i tile
//   Pk/Pkv: NB*NSEG*DM fp32   per-block partial sums (reduced inside band_out)
//   Wh/Wl : 4*128*128 bf16    split W (Wq,Wk,Wv,Wo), B-frag order
// ---------------------------------------------------------------------------

// Setup: blocks 0..127 pack W (B-frag, split hi/lo); 128..383 build WB.
__global__ __launch_bounds__(512) void setup_kernel(
    const float* __restrict__ Wq, const float* __restrict__ Wk,
    const float* __restrict__ Wv, const float* __restrict__ Wo,
    const float* __restrict__ pos_bias,
    ushort* __restrict__ Wh, ushort* __restrict__ Wl,
    ushort* __restrict__ WB)
{
    const int b = blockIdx.x;
    const int tid = threadIdx.x;
    if (b < 128) {
        // ---- pack Wq/Wk/Wv/Wo into B-frag order, split hi/lo bf16 ----
        const int id = b;                 // (mat*8+ct)*4+ks
        const int mat = id >> 5;
        const int ct = (id & 31) >> 2, ks = id & 3;
        const int lane = tid >> 3, j = tid & 7;
        const int k = ks * 32 + (lane >> 4) * 8 + j;
        const int col = ct * 16 + (lane & 15);
        const float* W = (mat == 0) ? Wq : ((mat == 1) ? Wk : ((mat == 2) ? Wv : Wo));
        float w = W[k * DM + col];
        ushort h = bf16_rne(w);
        Wh[(size_t)id * 512 + tid] = h;
        Wl[(size_t)id * 512 + tid] = bf16_rne(w - bf16_to_f(h));
    } else {
        // ---- banded weights in A-frag order per 16-i tile, 2 blocks/tile ----
        const int idx = b - 128;          // 0..255
        const int it = idx >> 1;          // 0..127
        const int half = idx & 1;
        const int i0 = it * 16;
        const int tend = half * 1280 + 1280;
        for (int t = half * 1280 + tid; t < tend; t += 512) {
            const int ks = t >> 9;
            const int lane = (t >> 3) & 63;
            const int jj = t & 7;
            const int m = lane & 15;
            const int k = ks * 32 + ((lane >> 4) << 3) + jj;
            const int i = i0 + m;
            const int j = i0 - 64 + k;
            const int rel = k - 64 - m;  // j - i
            float val = 0.f;
            if (rel > -WIN && rel < WIN && j >= 0 && j < SL)
                val = __expf(pos_bias[(size_t)i * SL + j]) - 1.f;
            WB[(size_t)it * 2560 + t] = bf16_rne(val);
        }
    }
}

// QKV projection via split-bf16 MFMA.
// Block = (n, 32 l's), 512 threads / 8 waves; wave w owns dt slice w (16 d's)
// for all 3 matrices, 2 l-tiles.
__global__ __launch_bounds__(512, 6) void qkv_kernel(
    const float* __restrict__ x,
    const ushort* __restrict__ Wh, const ushort* __restrict__ Wl,
    const float* __restrict__ bq, const float* __restrict__ bk,
    const float* __restrict__ bv,
    ushort* __restrict__ sqT, ushort* __restrict__ ekTF, ushort* __restrict__ ekvTF,
    float* __restrict__ Pk, float* __restrict__ Pkv)
{
    __shared__ ushort Ah[32 * 128];   // frag order: ((lt*4+ks)*64+lane)*8+j
    __shared__ ushort Al[32 * 128];
    const int n = blockIdx.y, bx = blockIdx.x, l0 = bx * 32;
    const int tid = threadIdx.x;
    const int wave = tid >> 6;        // = dt slice 0..7
    const int lane = tid & 63;

    // Pad-tile zeroing (front 4 + back 6 tiles per n), done by blocks bx<10.
    if (bx < 10) {
        const int jt_p = (bx < PADF) ? bx : (NT + bx);   // 0..3, 132..137
        const size_t zb = ((size_t)n * NTP + jt_p) * 2048 + (size_t)tid * 4;
        ushort4 z; z.x = 0; z.y = 0; z.z = 0; z.w = 0;
        *(ushort4*)&ekTF [zb] = z;
        *(ushort4*)&ekvTF[zb] = z;
    }

    // ---- stage x tile (32 l x 128 c) into A-frag order, split hi/lo ----
    {
        const int lo = tid & 31;          // l within tile
        const int cq = tid >> 5;          // 0..15, c0 = cq*8
        const int l  = l0 + lo;
        const int c0 = cq * 8;
        float xv[8];
        #pragma unroll
        for (int u = 0; u < 8; ++u)
            xv[u] = x[((size_t)n * DM + c0 + u) * SL + l];
        u16x8 hv, lv;
        #pragma unroll
        for (int u = 0; u < 8; ++u) {
            const ushort h = bf16_hi_trunc(xv[u]);
            hv[u] = h;
            lv[u] = bf16_rne(xv[u] - bf16_to_f(h));
        }
        const int lt = lo >> 4, m = lo & 15;
        const int ks = cq >> 2, oct = cq & 3;
        const int idx = ((lt * 4 + ks) * 64 + oct * 16 + m) * 8;
        *(u16x8*)&Ah[idx] = hv;
        *(u16x8*)&Al[idx] = lv;
    }
    __syncthreads();

    const int dcol = lane & 15;
    const int d = wave * 16 + dcol;

    f32x4 acc[3][2];
    {
        const float b0 = bq[d], b1 = bk[d], b2 = bv[d];
        #pragma unroll
        for (int lt = 0; lt < 2; ++lt) {
            acc[0][lt] = (f32x4){b0, b0, b0, b0};
            acc[1][lt] = (f32x4){b1, b1, b1, b1};
            acc[2][lt] = (f32x4){b2, b2, b2, b2};
        }
    }

    const bf16x8* WhV = (const bf16x8*)Wh;
    const bf16x8* WlV = (const bf16x8*)Wl;
    #pragma unroll
    for (int ks = 0; ks < 4; ++ks) {
        bf16x8 bh[3], bl[3];
        #pragma unroll
        for (int m = 0; m < 3; ++m) {
            const int fi = ((m * 8 + wave) * 4 + ks) * 64 + lane;
            bh[m] = WhV[fi];
            bl[m] = WlV[fi];
        }
        #pragma unroll
        for (int lt = 0; lt < 2; ++lt) {
            const bf16x8 ah = *(const bf16x8*)&Ah[((lt * 4 + ks) * 64 + lane) * 8];
            const bf16x8 al = *(const bf16x8*)&Al[((lt * 4 + ks) * 64 + lane) * 8];
            #pragma unroll
            for (int m = 0; m < 3; ++m) {
                acc[m][lt] = __builtin_amdgcn_mfma_f32_16x16x32_bf16(
                    ah, bh[m], acc[m][lt], 0, 0, 0);
                acc[m][lt] = __builtin_amdgcn_mfma_f32_16x16x32_bf16(
                    al, bh[m], acc[m][lt], 0, 0, 0);
                acc[m][lt] = __builtin_amdgcn_mfma_f32_16x16x32_bf16(
                    ah, bl[m], acc[m][lt], 0, 0, 0);
            }
        }
    }

    const int lrow0 = (lane >> 4) * 4;
    float psk = 0.f, pskv = 0.f;
    #pragma unroll
    for (int lt = 0; lt < 2; ++lt) {
        const f32x4 q4 = acc[0][lt];
        const f32x4 k4 = acc[1][lt];
        const f32x4 v4 = acc[2][lt];
        ushort eh[4], zh[4], sh[4];
        #pragma unroll
        for (int r = 0; r < 4; ++r) {
            const float e = __expf(k4[r]);
            const float z = e * v4[r];
            const float s = fminf(__builtin_amdgcn_rcpf(1.f + __expf(-q4[r])), 1.f);
            sh[r] = (ushort)(s * 65535.f + 0.5f);
            eh[r] = bf16_rne(e);
            zh[r] = bf16_rne(z);
            psk  += e;
            pskv += z;
        }
        // tiled stores: tile jt = bx*2 + lt, row d, jo = lrow0..lrow0+3
        const int jt = bx * 2 + lt;
        const size_t tb = ((size_t)n * NTP + PADF + jt) * 2048
                        + (size_t)d * 16 + lrow0;
        const size_t sb = ((size_t)n * NT + jt) * 2048
                        + (size_t)d * 16 + lrow0;
        ushort4 ev; ev.x = eh[0]; ev.y = eh[1]; ev.z = eh[2]; ev.w = eh[3];
        ushort4 zv; zv.x = zh[0]; zv.y = zh[1]; zv.z = zh[2]; zv.w = zh[3];
        ushort4 sv; sv.x = sh[0]; sv.y = sh[1]; sv.z = sh[2]; sv.w = sh[3];
        *(ushort4*)&ekTF [tb] = ev;
        *(ushort4*)&ekvTF[tb] = zv;
        *(ushort4*)&sqT  [sb] = sv;
    }
    {
        float a = psk, b = pskv;
        a += __shfl_xor(a, 16, 64); a += __shfl_xor(a, 32, 64);
        b += __shfl_xor(b, 16, 64); b += __shfl_xor(b, 32, 64);
        if (lane < 16) {
            const size_t o = ((size_t)n * NSEG + bx) * DM + d;
            Pk [o] = a;
            Pkv[o] = b;
        }
    }
}

// FUSED band correction + output projection, wave-local handoff.
// Phase 1 is dt-outer / ks-inner: only ONE den/num pair (8 VGPR) live at a
// time instead of 64, freeing ~56 VGPRs for in-flight L2 loads so the 10
// loads of each dt pipeline under the previous dt's MFMAs.
__global__ __launch_bounds__(256, 4) void band_out_kernel(
    const ushort* __restrict__ ekTF, const ushort* __restrict__ ekvTF,
    const ushort* __restrict__ WB,
    const float* __restrict__ Pk, const float* __restrict__ Pkv,
    const ushort* __restrict__ sqT,
    const ushort* __restrict__ Wh, const ushort* __restrict__ Wl,
    const float* __restrict__ bo, float* __restrict__ out)
{
    __shared__ __align__(16) union {
        float ylds[64 * YST];   // y fp32, [row l_local][col d]
        float ot[128 * OST];    // out transpose buffer [c][l_local]
    } u;
    __shared__ float SkL[DM], SkvL[DM];

    const int bid = blockIdx.x;          // 0..1023
    const int xcd = bid & 7;
    const int slot = bid >> 3;           // 0..127
    const int nsub = slot >> 5;          // 0..3
    const int itg  = slot & 31;          // 0..31
    const int n = xcd * 4 + nsub;        // 4 n's per XCD
    const int wave = threadIdx.x >> 6;
    const int lane = threadIdx.x & 63;
    const int it = itg * 4 + wave;       // 0..127
    const int l0 = itg * 64;

    const int dcol = lane & 15;
    const int jgrp8 = (lane >> 4) << 3;

    // Hoist all 5 WB A-fragments (hides L2 latency under the Pk reduction).
    const bf16x8* WBv = (const bf16x8*)(WB + (size_t)it * 2560);
    bf16x8 aWB[5];
    #pragma unroll
    for (int ks = 0; ks < 5; ++ks) aWB[ks] = WBv[ks * 64 + lane];

    // ---- Reduce Pk/Pkv -> SkL/SkvL (threads 0-127: Sk, 128-255: Skv) ----
    {
        const int tdd = threadIdx.x & 127;
        const float* P = (threadIdx.x < 128) ? Pk : Pkv;
        float s = 0.f;
        #pragma unroll
        for (int seg = 0; seg < NSEG; ++seg)
            s += P[((size_t)n * NSEG + seg) * DM + tdd];
        if (threadIdx.x < 128) SkL[tdd] = s; else SkvL[tdd] = s;
    }
    __syncthreads();

    // ---- Phase 1: banded MFMA, dt-outer; gate + ylds write fused per dt ----
    // lane-dependent tile select: jt_p = it + 2ks + (lane>>5); jo = ((lane>>4)&1)*8
    const size_t lsel = (size_t)(lane >> 5) * 2048 + (size_t)((lane >> 4) & 1) * 8
                      + (size_t)dcol * 16;
    size_t tb[5];
    #pragma unroll
    for (int ks = 0; ks < 5; ++ks)
        tb[ks] = ((size_t)n * NTP + it + 2 * ks) * 2048 + lsel;

    const int irow0 = (lane >> 4) << 2;
    const size_t sgb = ((size_t)n * NT + it) * 2048 + irow0;

    #pragma unroll
    for (int dt = 0; dt < 8; ++dt) {
        const int d = dt * 16 + dcol;
        const float sk = SkL[d];
        const float sv = SkvL[d];
        f32x4 den = (f32x4){sk, sk, sk, sk};
        f32x4 num = (f32x4){sv, sv, sv, sv};
        #pragma unroll
        for (int ks = 0; ks < 5; ++ks) {
            const size_t rbase = tb[ks] + (size_t)dt * 256;   // dt*16 rows * 16 jo
            const bf16x8 bden = *(const bf16x8*)(ekTF  + rbase);
            const bf16x8 bnum = *(const bf16x8*)(ekvTF + rbase);
            den = __builtin_amdgcn_mfma_f32_16x16x32_bf16(aWB[ks], bden, den, 0, 0, 0);
            num = __builtin_amdgcn_mfma_f32_16x16x32_bf16(aWB[ks], bnum, num, 0, 0, 0);
        }
        // Gate with sigmoid(q) (unorm16 tiled); write y slice to LDS stripe.
        const ushort4 s4 = *(const ushort4*)&sqT[sgb + (size_t)d * 16];
        float sf[4];
        sf[0] = (float)s4.x; sf[1] = (float)s4.y;
        sf[2] = (float)s4.z; sf[3] = (float)s4.w;
        #pragma unroll
        for (int r = 0; r < 4; ++r) {
            const float s = sf[r] * (1.f / 65535.f);
            const float y = s * num[r] * __builtin_amdgcn_rcpf(den[r]);
            u.ylds[(wave * 16 + irow0 + r) * YST + d] = y;
        }
    }

    // ---- Handoff: read own stripe in A-octet order, convert immediately ----
    bf16x8 yh[4], yl[4];
    {
        const int arow = wave * 16 + (lane & 15);
        #pragma unroll
        for (int ks = 0; ks < 4; ++ks) {
            const int base = arow * YST + ks * 32 + jgrp8;
            const float4 a0 = *(const float4*)&u.ylds[base];
            const float4 a1 = *(const float4*)&u.ylds[base + 4];
            float af[8];
            af[0] = a0.x; af[1] = a0.y; af[2] = a0.z; af[3] = a0.w;
            af[4] = a1.x; af[5] = a1.y; af[6] = a1.z; af[7] = a1.w;
            #pragma unroll
            for (int t = 0; t < 8; ++t) {
                const ushort h = bf16_hi_trunc(af[t]);
                yh[ks][t] = (short)h;
                yl[ks][t] = (short)bf16_rne(af[t] - bf16_to_f(h));
            }
        }
    }
    __syncthreads();   // all waves done with ylds; ot may now overwrite

    // ---- Phase 2: out projection, ct-outer (one acc live at a time) ----
    const bf16x8* WhV = (const bf16x8*)Wh;
    const bf16x8* WlV = (const bf16x8*)Wl;
    #pragma unroll
    for (int ct = 0; ct < 8; ++ct) {
        const float b0 = bo[ct * 16 + dcol];
        f32x4 acc = (f32x4){b0, b0, b0, b0};
        #pragma unroll
        for (int ks = 0; ks < 4; ++ks) {
            const int fi = ((24 + ct) * 4 + ks) * 64 + lane;  // mat=3 (Wo)
            const bf16x8 bh = WhV[fi];
            const bf16x8 bl = WlV[fi];
            acc = __builtin_amdgcn_mfma_f32_16x16x32_bf16(yh[ks], bh, acc, 0, 0, 0);
            acc = __builtin_amdgcn_mfma_f32_16x16x32_bf16(yl[ks], bh, acc, 0, 0, 0);
            acc = __builtin_amdgcn_mfma_f32_16x16x32_bf16(yh[ks], bl, acc, 0, 0, 0);
        }
        // Transpose through LDS: ot[c][l_local]; C rows = wave's 16 l's.
        const int c = ct * 16 + dcol;
        #pragma unroll
        for (int r = 0; r < 4; ++r)
            u.ot[c * OST + wave * 16 + irow0 + r] = acc[r];
    }
    __syncthreads();

    // Coalesced float4 store: 64 contiguous floats per c row, 8 reps.
    const int tid = threadIdx.x;
    #pragma unroll
    for (int rep = 0; rep < 8; ++rep) {
        const int e = rep * 256 + tid;   // 0..2047
        const int c = e >> 4;            // 0..127
        const int lq = e & 15;           // 0..15 -> 4-float chunk
        const float4 v = *(const float4*)&u.ot[c * OST + lq * 4];
        *(float4*)&out[((size_t)n * DM + c) * SL + l0 + lq * 4] = v;
    }
}

extern "C" void kernel_launch(void* const* d_in, const int* in_sizes, int n_in,
                              void* d_out, int out_size, void* d_ws, size_t ws_size,
                              hipStream_t stream)
{
    const float* x        = (const float*)d_in[0];
    const float* Wq       = (const float*)d_in[1];
    const float* bq       = (const float*)d_in[2];
    const float* Wk       = (const float*)d_in[3];
    const float* bk       = (const float*)d_in[4];
    const float* Wv       = (const float*)d_in[5];
    const float* bv       = (const float*)d_in[6];
    const float* Wo       = (const float*)d_in[7];
    const float* bo       = (const float*)d_in[8];
    const float* pos_bias = (const float*)d_in[9];
    float* out = (float*)d_out;

    ushort* sqT   = (ushort*)d_ws;                       // NB*NT*2048 ushorts
    ushort* ekTF  = sqT   + (size_t)NB * NT * 2048;
    ushort* ekvTF = ekTF  + (size_t)NB * NTP * 2048;
    ushort* WB    = ekvTF + (size_t)NB * NTP * 2048;
    float*  Pk    = (float*)(WB + (size_t)128 * 2560);
    float*  Pkv   = Pk   + (size_t)NB * NSEG * DM;
    ushort* Wh    = (ushort*)(Pkv + (size_t)NB * NSEG * DM);
    ushort* Wl    = Wh + (size_t)4 * DM * DM;

    setup_kernel   <<<dim3(384),      512, 0, stream>>>(Wq, Wk, Wv, Wo, pos_bias,
                                                        Wh, Wl, WB);
    qkv_kernel     <<<dim3(NSEG, NB), 512, 0, stream>>>(x, Wh, Wl, bq, bk, bv,
                                                        sqT, ekTF, ekvTF, Pk, Pkv);
    band_out_kernel<<<dim3(NB * 32),  256, 0, stream>>>(ekTF, ekvTF, WB, Pk, Pkv, sqT,
                                                        Wh, Wl, bo, out);
}

// Round 8
// 155.767 us; speedup vs baseline: 1.0290x; 1.0232x over previous
//
#include <hip/hip_runtime.h>
#include <hip/hip_bf16.h>
#include <math.h>

#define NB 32
#define DM 128
#define SL 2048
#define WIN 64
#define NT  (SL / 16)    // 128 j-tiles of 16
#define PADF 4           // front pad tiles (j in [-64,0))
#define PADB 6           // back pad tiles  (j in [SL, SL+96))
#define NTP (NT + PADF + PADB)   // 138 tiles per (n)
#define YST 132          // ylds row stride (floats)
#define OST 68           // ot row stride (floats, 16B-aligned rows, 2-way banks)
#define NSEG 64          // qkv l-blocks per n (SL/32)

typedef __attribute__((ext_vector_type(8))) short bf16x8;
typedef __attribute__((ext_vector_type(8))) unsigned short u16x8;
typedef __attribute__((ext_vector_type(4))) float f32x4;
typedef __attribute__((ext_vector_type(4))) unsigned int u32x4;

__device__ inline ushort bf16_rne(float f) {
    union { float f; unsigned u; } v; v.f = f;
    unsigned u = v.u;
    return (ushort)((u + 0x7FFFu + ((u >> 16) & 1u)) >> 16);
}
__device__ inline float bf16_to_f(ushort h) {
    union { unsigned u; float f; } v; v.u = ((unsigned)h) << 16;
    return v.f;
}
// Hardware packed f32->bf16 RNE (v_cvt_pk_bf16_f32): a -> low16, b -> high16.
__device__ inline unsigned pk_bf16(float a, float b) {
    union { __hip_bfloat162 h; unsigned u; } v;
    v.h = __float22bfloat162_rn(make_float2(a, b));
    return v.u;
}

// ---------------------------------------------------------------------------
// ws layout:
//   sqT   : NB*NT*2048 ushort sigmoid(q) as unorm16, TILED [n][jt][d][jo]
//   ekTF  : NB*NTP*2048 bf16  exp(k) in 16-j x 128-d tiles [n][jt][d][jo],
//                             jt offset by PADF; pad tiles zeroed by qkv bx<10
//   ekvTF : same              exp(k)*v
//   WB    : 128*2560 bf16     banded weights, A-frag order per 16-i tile
//   Pk/Pkv: NB*NSEG*DM fp32   per-block partial sums (reduced inside band_out)
//   Wh/Wl : 4*128*128 bf16    split W (Wq,Wk,Wv,Wo), B-frag order
// ---------------------------------------------------------------------------

// Setup: blocks 0..127 pack W (B-frag, split hi/lo); 128..383 build WB.
__global__ __launch_bounds__(512) void setup_kernel(
    const float* __restrict__ Wq, const float* __restrict__ Wk,
    const float* __restrict__ Wv, const float* __restrict__ Wo,
    const float* __restrict__ pos_bias,
    ushort* __restrict__ Wh, ushort* __restrict__ Wl,
    ushort* __restrict__ WB)
{
    const int b = blockIdx.x;
    const int tid = threadIdx.x;
    if (b < 128) {
        // ---- pack Wq/Wk/Wv/Wo into B-frag order, split hi/lo bf16 ----
        const int id = b;                 // (mat*8+ct)*4+ks
        const int mat = id >> 5;
        const int ct = (id & 31) >> 2, ks = id & 3;
        const int lane = tid >> 3, j = tid & 7;
        const int k = ks * 32 + (lane >> 4) * 8 + j;
        const int col = ct * 16 + (lane & 15);
        const float* W = (mat == 0) ? Wq : ((mat == 1) ? Wk : ((mat == 2) ? Wv : Wo));
        float w = W[k * DM + col];
        ushort h = bf16_rne(w);
        Wh[(size_t)id * 512 + tid] = h;
        Wl[(size_t)id * 512 + tid] = bf16_rne(w - bf16_to_f(h));
    } else {
        // ---- banded weights in A-frag order per 16-i tile, 2 blocks/tile ----
        const int idx = b - 128;          // 0..255
        const int it = idx >> 1;          // 0..127
        const int half = idx & 1;
        const int i0 = it * 16;
        const int tend = half * 1280 + 1280;
        for (int t = half * 1280 + tid; t < tend; t += 512) {
            const int ks = t >> 9;
            const int lane = (t >> 3) & 63;
            const int jj = t & 7;
            const int m = lane & 15;
            const int k = ks * 32 + ((lane >> 4) << 3) + jj;
            const int i = i0 + m;
            const int j = i0 - 64 + k;
            const int rel = k - 64 - m;  // j - i
            float val = 0.f;
            if (rel > -WIN && rel < WIN && j >= 0 && j < SL)
                val = __expf(pos_bias[(size_t)i * SL + j]) - 1.f;
            WB[(size_t)it * 2560 + t] = bf16_rne(val);
        }
    }
}

// QKV projection via split-bf16 MFMA.
// Block = (n, 32 l's), 512 threads / 8 waves; wave w owns dt slice w (16 d's)
// for all 3 matrices, 2 l-tiles. All f32->bf16 conversions use the HW
// packed cvt (v_cvt_pk_bf16_f32) instead of the 5-op software RNE.
__global__ __launch_bounds__(512, 6) void qkv_kernel(
    const float* __restrict__ x,
    const ushort* __restrict__ Wh, const ushort* __restrict__ Wl,
    const float* __restrict__ bq, const float* __restrict__ bk,
    const float* __restrict__ bv,
    ushort* __restrict__ sqT, ushort* __restrict__ ekTF, ushort* __restrict__ ekvTF,
    float* __restrict__ Pk, float* __restrict__ Pkv)
{
    __shared__ ushort Ah[32 * 128];   // frag order: ((lt*4+ks)*64+lane)*8+j
    __shared__ ushort Al[32 * 128];
    const int n = blockIdx.y, bx = blockIdx.x, l0 = bx * 32;
    const int tid = threadIdx.x;
    const int wave = tid >> 6;        // = dt slice 0..7
    const int lane = tid & 63;

    // Pad-tile zeroing (front 4 + back 6 tiles per n), done by blocks bx<10.
    if (bx < 10) {
        const int jt_p = (bx < PADF) ? bx : (NT + bx);   // 0..3, 132..137
        const size_t zb = ((size_t)n * NTP + jt_p) * 2048 + (size_t)tid * 4;
        ushort4 z; z.x = 0; z.y = 0; z.z = 0; z.w = 0;
        *(ushort4*)&ekTF [zb] = z;
        *(ushort4*)&ekvTF[zb] = z;
    }

    // ---- stage x tile (32 l x 128 c) into A-frag order, split hi/lo ----
    {
        const int lo = tid & 31;          // l within tile
        const int cq = tid >> 5;          // 0..15, c0 = cq*8
        const int l  = l0 + lo;
        const int c0 = cq * 8;
        float xv[8];
        #pragma unroll
        for (int u = 0; u < 8; ++u)
            xv[u] = x[((size_t)n * DM + c0 + u) * SL + l];
        unsigned xb[8];
        #pragma unroll
        for (int u = 0; u < 8; ++u) xb[u] = __float_as_uint(xv[u]);
        unsigned hv32[4], lv32[4];
        #pragma unroll
        for (int p = 0; p < 4; ++p) {
            hv32[p] = (xb[2 * p] >> 16) | (xb[2 * p + 1] & 0xFFFF0000u);
            const float r0 = xv[2 * p]     - __uint_as_float(xb[2 * p]     & 0xFFFF0000u);
            const float r1 = xv[2 * p + 1] - __uint_as_float(xb[2 * p + 1] & 0xFFFF0000u);
            lv32[p] = pk_bf16(r0, r1);
        }
        const int lt = lo >> 4, m = lo & 15;
        const int ks = cq >> 2, oct = cq & 3;
        const int idx = ((lt * 4 + ks) * 64 + oct * 16 + m) * 8;
        *(uint4*)&Ah[idx] = make_uint4(hv32[0], hv32[1], hv32[2], hv32[3]);
        *(uint4*)&Al[idx] = make_uint4(lv32[0], lv32[1], lv32[2], lv32[3]);
    }
    __syncthreads();

    const int dcol = lane & 15;
    const int d = wave * 16 + dcol;

    f32x4 acc[3][2];
    {
        const float b0 = bq[d], b1 = bk[d], b2 = bv[d];
        #pragma unroll
        for (int lt = 0; lt < 2; ++lt) {
            acc[0][lt] = (f32x4){b0, b0, b0, b0};
            acc[1][lt] = (f32x4){b1, b1, b1, b1};
            acc[2][lt] = (f32x4){b2, b2, b2, b2};
        }
    }

    const bf16x8* WhV = (const bf16x8*)Wh;
    const bf16x8* WlV = (const bf16x8*)Wl;
    #pragma unroll
    for (int ks = 0; ks < 4; ++ks) {
        bf16x8 bh[3], bl[3];
        #pragma unroll
        for (int m = 0; m < 3; ++m) {
            const int fi = ((m * 8 + wave) * 4 + ks) * 64 + lane;
            bh[m] = WhV[fi];
            bl[m] = WlV[fi];
        }
        #pragma unroll
        for (int lt = 0; lt < 2; ++lt) {
            const bf16x8 ah = *(const bf16x8*)&Ah[((lt * 4 + ks) * 64 + lane) * 8];
            const bf16x8 al = *(const bf16x8*)&Al[((lt * 4 + ks) * 64 + lane) * 8];
            #pragma unroll
            for (int m = 0; m < 3; ++m) {
                acc[m][lt] = __builtin_amdgcn_mfma_f32_16x16x32_bf16(
                    ah, bh[m], acc[m][lt], 0, 0, 0);
                acc[m][lt] = __builtin_amdgcn_mfma_f32_16x16x32_bf16(
                    al, bh[m], acc[m][lt], 0, 0, 0);
                acc[m][lt] = __builtin_amdgcn_mfma_f32_16x16x32_bf16(
                    ah, bl[m], acc[m][lt], 0, 0, 0);
            }
        }
    }

    const int lrow0 = (lane >> 4) * 4;
    float psk = 0.f, pskv = 0.f;
    #pragma unroll
    for (int lt = 0; lt < 2; ++lt) {
        const f32x4 q4 = acc[0][lt];
        const f32x4 k4 = acc[1][lt];
        const f32x4 v4 = acc[2][lt];
        float e[4], z[4];
        unsigned su[4];
        #pragma unroll
        for (int r = 0; r < 4; ++r) {
            e[r] = __expf(k4[r]);
            z[r] = e[r] * v4[r];
            const float s = fminf(__builtin_amdgcn_rcpf(1.f + __expf(-q4[r])), 1.f);
            su[r] = (unsigned)(s * 65535.f + 0.5f);
            psk  += e[r];
            pskv += z[r];
        }
        // tiled stores: tile jt = bx*2 + lt, row d, jo = lrow0..lrow0+3
        const int jt = bx * 2 + lt;
        const size_t tb = ((size_t)n * NTP + PADF + jt) * 2048
                        + (size_t)d * 16 + lrow0;
        const size_t sb = ((size_t)n * NT + jt) * 2048
                        + (size_t)d * 16 + lrow0;
        *(uint2*)&ekTF [tb] = make_uint2(pk_bf16(e[0], e[1]), pk_bf16(e[2], e[3]));
        *(uint2*)&ekvTF[tb] = make_uint2(pk_bf16(z[0], z[1]), pk_bf16(z[2], z[3]));
        *(uint2*)&sqT  [sb] = make_uint2(su[0] | (su[1] << 16), su[2] | (su[3] << 16));
    }
    {
        float a = psk, b = pskv;
        a += __shfl_xor(a, 16, 64); a += __shfl_xor(a, 32, 64);
        b += __shfl_xor(b, 16, 64); b += __shfl_xor(b, 32, 64);
        if (lane < 16) {
            const size_t o = ((size_t)n * NSEG + bx) * DM + d;
            Pk [o] = a;
            Pkv[o] = b;
        }
    }
}

// FUSED band correction + output projection, wave-local handoff.
// Pk reduction uses float4 loads + 4-way LDS tree (16 VMEM ops/thread).
// Handoff conversion uses HW packed cvt.
__global__ __launch_bounds__(256, 4) void band_out_kernel(
    const ushort* __restrict__ ekTF, const ushort* __restrict__ ekvTF,
    const ushort* __restrict__ WB,
    const float* __restrict__ Pk, const float* __restrict__ Pkv,
    const ushort* __restrict__ sqT,
    const ushort* __restrict__ Wh, const ushort* __restrict__ Wl,
    const float* __restrict__ bo, float* __restrict__ out)
{
    __shared__ __align__(16) union {
        float ylds[64 * YST];   // y fp32, [row l_local][col d]
        float ot[128 * OST];    // out transpose buffer [c][l_local]
        float red[8][DM];       // Pk-reduction scratch (used before ylds)
    } u;
    __shared__ float SkL[DM], SkvL[DM];

    const int bid = blockIdx.x;          // 0..1023
    const int xcd = bid & 7;
    const int slot = bid >> 3;           // 0..127
    const int nsub = slot >> 5;          // 0..3
    const int itg  = slot & 31;          // 0..31
    const int n = xcd * 4 + nsub;        // 4 n's per XCD
    const int wave = threadIdx.x >> 6;
    const int lane = threadIdx.x & 63;
    const int it = itg * 4 + wave;       // 0..127
    const int l0 = itg * 64;

    const int dcol = lane & 15;
    const int jgrp8 = (lane >> 4) << 3;

    // Hoist all 5 WB A-fragments (hides L2 latency under the Pk reduction).
    const bf16x8* WBv = (const bf16x8*)(WB + (size_t)it * 2560);
    bf16x8 aWB[5];
    #pragma unroll
    for (int ks = 0; ks < 5; ++ks) aWB[ks] = WBv[ks * 64 + lane];

    // ---- Reduce Pk/Pkv -> SkL/SkvL via float4 loads + 4-way LDS tree ----
    {
        const int tid = threadIdx.x;
        const int q = tid & 31;          // d-quad 0..31
        const int g = tid >> 5;          // 0..7: g<4 -> Sk segs, g>=4 -> Skv
        const float* P = (g < 4) ? Pk : Pkv;
        const int s0 = (g & 3) * 16;
        f32x4 a4 = (f32x4){0.f, 0.f, 0.f, 0.f};
        #pragma unroll
        for (int s = 0; s < 16; ++s) {
            const f32x4 v = *(const f32x4*)&P[((size_t)n * NSEG + s0 + s) * DM + q * 4];
            a4 += v;
        }
        *(f32x4*)&u.red[g][q * 4] = a4;
    }
    __syncthreads();
    {
        const int tid = threadIdx.x;
        if (tid < 128)
            SkL[tid]  = u.red[0][tid] + u.red[1][tid] + u.red[2][tid] + u.red[3][tid];
        else {
            const int dd = tid - 128;
            SkvL[dd] = u.red[4][dd] + u.red[5][dd] + u.red[6][dd] + u.red[7][dd];
        }
    }
    __syncthreads();

    // ---- Phase 1: banded MFMA, dt-outer; gate + ylds write fused per dt ----
    // lane-dependent tile select: jt_p = it + 2ks + (lane>>5); jo = ((lane>>4)&1)*8
    const size_t lsel = (size_t)(lane >> 5) * 2048 + (size_t)((lane >> 4) & 1) * 8
                      + (size_t)dcol * 16;
    size_t tb[5];
    #pragma unroll
    for (int ks = 0; ks < 5; ++ks)
        tb[ks] = ((size_t)n * NTP + it + 2 * ks) * 2048 + lsel;

    const int irow0 = (lane >> 4) << 2;
    const size_t sgb = ((size_t)n * NT + it) * 2048 + irow0;

    #pragma unroll
    for (int dt = 0; dt < 8; ++dt) {
        const int d = dt * 16 + dcol;
        const float sk = SkL[d];
        const float sv = SkvL[d];
        f32x4 den = (f32x4){sk, sk, sk, sk};
        f32x4 num = (f32x4){sv, sv, sv, sv};
        #pragma unroll
        for (int ks = 0; ks < 5; ++ks) {
            const size_t rbase = tb[ks] + (size_t)dt * 256;   // dt*16 rows * 16 jo
            const bf16x8 bden = *(const bf16x8*)(ekTF  + rbase);
            const bf16x8 bnum = *(const bf16x8*)(ekvTF + rbase);
            den = __builtin_amdgcn_mfma_f32_16x16x32_bf16(aWB[ks], bden, den, 0, 0, 0);
            num = __builtin_amdgcn_mfma_f32_16x16x32_bf16(aWB[ks], bnum, num, 0, 0, 0);
        }
        // Gate with sigmoid(q) (unorm16 tiled); write y slice to LDS stripe.
        const ushort4 s4 = *(const ushort4*)&sqT[sgb + (size_t)d * 16];
        float sf[4];
        sf[0] = (float)s4.x; sf[1] = (float)s4.y;
        sf[2] = (float)s4.z; sf[3] = (float)s4.w;
        #pragma unroll
        for (int r = 0; r < 4; ++r) {
            const float s = sf[r] * (1.f / 65535.f);
            const float y = s * num[r] * __builtin_amdgcn_rcpf(den[r]);
            u.ylds[(wave * 16 + irow0 + r) * YST + d] = y;
        }
    }

    // ---- Handoff: read own stripe in A-octet order, convert via HW cvt ----
    bf16x8 yh[4], yl[4];
    {
        const int arow = wave * 16 + (lane & 15);
        #pragma unroll
        for (int ks = 0; ks < 4; ++ks) {
            const int base = arow * YST + ks * 32 + jgrp8;
            const float4 a0 = *(const float4*)&u.ylds[base];
            const float4 a1 = *(const float4*)&u.ylds[base + 4];
            float af[8];
            af[0] = a0.x; af[1] = a0.y; af[2] = a0.z; af[3] = a0.w;
            af[4] = a1.x; af[5] = a1.y; af[6] = a1.z; af[7] = a1.w;
            unsigned ab[8];
            #pragma unroll
            for (int t = 0; t < 8; ++t) ab[t] = __float_as_uint(af[t]);
            unsigned hw[4], lw[4];
            #pragma unroll
            for (int p = 0; p < 4; ++p) {
                hw[p] = (ab[2 * p] >> 16) | (ab[2 * p + 1] & 0xFFFF0000u);
                const float r0 = af[2 * p]     - __uint_as_float(ab[2 * p]     & 0xFFFF0000u);
                const float r1 = af[2 * p + 1] - __uint_as_float(ab[2 * p + 1] & 0xFFFF0000u);
                lw[p] = pk_bf16(r0, r1);
            }
            union { u32x4 w; bf16x8 b; } ch, cl;
            ch.w = (u32x4){hw[0], hw[1], hw[2], hw[3]};
            cl.w = (u32x4){lw[0], lw[1], lw[2], lw[3]};
            yh[ks] = ch.b;
            yl[ks] = cl.b;
        }
    }
    __syncthreads();   // all waves done with ylds; ot may now overwrite

    // ---- Phase 2: out projection, ct-outer (one acc live at a time) ----
    const bf16x8* WhV = (const bf16x8*)Wh;
    const bf16x8* WlV = (const bf16x8*)Wl;
    #pragma unroll
    for (int ct = 0; ct < 8; ++ct) {
        const float b0 = bo[ct * 16 + dcol];
        f32x4 acc = (f32x4){b0, b0, b0, b0};
        #pragma unroll
        for (int ks = 0; ks < 4; ++ks) {
            const int fi = ((24 + ct) * 4 + ks) * 64 + lane;  // mat=3 (Wo)
            const bf16x8 bh = WhV[fi];
            const bf16x8 bl = WlV[fi];
            acc = __builtin_amdgcn_mfma_f32_16x16x32_bf16(yh[ks], bh, acc, 0, 0, 0);
            acc = __builtin_amdgcn_mfma_f32_16x16x32_bf16(yl[ks], bh, acc, 0, 0, 0);
            acc = __builtin_amdgcn_mfma_f32_16x16x32_bf16(yh[ks], bl, acc, 0, 0, 0);
        }
        // Transpose through LDS: ot[c][l_local]; C rows = wave's 16 l's.
        const int c = ct * 16 + dcol;
        #pragma unroll
        for (int r = 0; r < 4; ++r)
            u.ot[c * OST + wave * 16 + irow0 + r] = acc[r];
    }
    __syncthreads();

    // Coalesced float4 store: 64 contiguous floats per c row, 8 reps.
    const int tid = threadIdx.x;
    #pragma unroll
    for (int rep = 0; rep < 8; ++rep) {
        const int e = rep * 256 + tid;   // 0..2047
        const int c = e >> 4;            // 0..127
        const int lq = e & 15;           // 0..15 -> 4-float chunk
        const float4 v = *(const float4*)&u.ot[c * OST + lq * 4];
        *(float4*)&out[((size_t)n * DM + c) * SL + l0 + lq * 4] = v;
    }
}

extern "C" void kernel_launch(void* const* d_in, const int* in_sizes, int n_in,
                              void* d_out, int out_size, void* d_ws, size_t ws_size,
                              hipStream_t stream)
{
    const float* x        = (const float*)d_in[0];
    const float* Wq       = (const float*)d_in[1];
    const float* bq       = (const float*)d_in[2];
    const float* Wk       = (const float*)d_in[3];
    const float* bk       = (const float*)d_in[4];
    const float* Wv       = (const float*)d_in[5];
    const float* bv       = (const float*)d_in[6];
    const float* Wo       = (const float*)d_in[7];
    const float* bo       = (const float*)d_in[8];
    const float* pos_bias = (const float*)d_in[9];
    float* out = (float*)d_out;

    ushort* sqT   = (ushort*)d_ws;                       // NB*NT*2048 ushorts
    ushort* ekTF  = sqT   + (size_t)NB * NT * 2048;
    ushort* ekvTF = ekTF  + (size_t)NB * NTP * 2048;
    ushort* WB    = ekvTF + (size_t)NB * NTP * 2048;
    float*  Pk    = (float*)(WB + (size_t)128 * 2560);
    float*  Pkv   = Pk   + (size_t)NB * NSEG * DM;
    ushort* Wh    = (ushort*)(Pkv + (size_t)NB * NSEG * DM);
    ushort* Wl    = Wh + (size_t)4 * DM * DM;

    setup_kernel   <<<dim3(384),      512, 0, stream>>>(Wq, Wk, Wv, Wo, pos_bias,
                                                        Wh, Wl, WB);
    qkv_kernel     <<<dim3(NSEG, NB), 512, 0, stream>>>(x, Wh, Wl, bq, bk, bv,
                                                        sqT, ekTF, ekvTF, Pk, Pkv);
    band_out_kernel<<<dim3(NB * 32),  256, 0, stream>>>(ekTF, ekvTF, WB, Pk, Pkv, sqT,
                                                        Wh, Wl, bo, out);
}

// Round 9
// 145.759 us; speedup vs baseline: 1.0996x; 1.0687x over previous
//
#include <hip/hip_runtime.h>
#include <hip/hip_bf16.h>
#include <math.h>

#define NB 32
#define DM 128
#define SL 2048
#define WIN 64
#define NT  (SL / 16)    // 128 j-tiles of 16
#define PADF 4           // front pad tiles (j in [-64,0))
#define PADB 6           // back pad tiles  (j in [SL, SL+96))
#define NTP (NT + PADF + PADB)   // 138 tiles per (n)
#define YST 132          // ylds row stride (floats)
#define OST 68           // ot row stride (floats, 16B-aligned rows, 2-way banks)
#define TPB 8            // 32-l tiles per qkv block
#define QBX 8            // qkv blocks per n (QBX*TPB*32 = 2048)

typedef __attribute__((ext_vector_type(8))) short bf16x8;
typedef __attribute__((ext_vector_type(4))) float f32x4;
typedef __attribute__((ext_vector_type(4))) unsigned int u32x4;

__device__ inline ushort bf16_rne(float f) {
    union { float f; unsigned u; } v; v.f = f;
    unsigned u = v.u;
    return (ushort)((u + 0x7FFFu + ((u >> 16) & 1u)) >> 16);
}
__device__ inline float bf16_to_f(ushort h) {
    union { unsigned u; float f; } v; v.u = ((unsigned)h) << 16;
    return v.f;
}
// Hardware packed f32->bf16 RNE (v_cvt_pk_bf16_f32): a -> low16, b -> high16.
__device__ inline unsigned pk_bf16(float a, float b) {
    union { __hip_bfloat162 h; unsigned u; } v;
    v.h = __float22bfloat162_rn(make_float2(a, b));
    return v.u;
}

// ---------------------------------------------------------------------------
// ws layout:
//   sqT   : NB*NT*2048 ushort sigmoid(q) as unorm16, TILED [n][jt][d][jo]
//   ekTF  : NB*NTP*2048 bf16  exp(k) in 16-j x 128-d tiles [n][jt][d][jo],
//                             jt offset by PADF; pad tiles zeroed by qkv
//   ekvTF : same              exp(k)*v
//   WB    : 128*2560 bf16     banded weights, A-frag order per 16-i tile
//   Pk/Pkv: NB*QBX*DM fp32    per-block partial sums (reduced inside band_out)
//   Wh/Wl : 4*128*128 bf16    split W (Wq,Wk,Wv,Wo), B-frag order
// ---------------------------------------------------------------------------

// Setup: blocks 0..127 pack W (B-frag, split hi/lo); 128..383 build WB.
__global__ __launch_bounds__(512) void setup_kernel(
    const float* __restrict__ Wq, const float* __restrict__ Wk,
    const float* __restrict__ Wv, const float* __restrict__ Wo,
    const float* __restrict__ pos_bias,
    ushort* __restrict__ Wh, ushort* __restrict__ Wl,
    ushort* __restrict__ WB)
{
    const int b = blockIdx.x;
    const int tid = threadIdx.x;
    if (b < 128) {
        // ---- pack Wq/Wk/Wv/Wo into B-frag order, split hi/lo bf16 ----
        const int id = b;                 // (mat*8+ct)*4+ks
        const int mat = id >> 5;
        const int ct = (id & 31) >> 2, ks = id & 3;
        const int lane = tid >> 3, j = tid & 7;
        const int k = ks * 32 + (lane >> 4) * 8 + j;
        const int col = ct * 16 + (lane & 15);
        const float* W = (mat == 0) ? Wq : ((mat == 1) ? Wk : ((mat == 2) ? Wv : Wo));
        float w = W[k * DM + col];
        ushort h = bf16_rne(w);
        Wh[(size_t)id * 512 + tid] = h;
        Wl[(size_t)id * 512 + tid] = bf16_rne(w - bf16_to_f(h));
    } else {
        // ---- banded weights in A-frag order per 16-i tile, 2 blocks/tile ----
        const int idx = b - 128;          // 0..255
        const int it = idx >> 1;          // 0..127
        const int half = idx & 1;
        const int i0 = it * 16;
        const int tend = half * 1280 + 1280;
        for (int t = half * 1280 + tid; t < tend; t += 512) {
            const int ks = t >> 9;
            const int lane = (t >> 3) & 63;
            const int jj = t & 7;
            const int m = lane & 15;
            const int k = ks * 32 + ((lane >> 4) << 3) + jj;
            const int i = i0 + m;
            const int j = i0 - 64 + k;
            const int rel = k - 64 - m;  // j - i
            float val = 0.f;
            if (rel > -WIN && rel < WIN && j >= 0 && j < SL)
                val = __expf(pos_bias[(size_t)i * SL + j]) - 1.f;
            WB[(size_t)it * 2560 + t] = bf16_rne(val);
        }
    }
}

// QKV projection via split-bf16 MFMA, weight-amortized.
// Block = (n, 256 l's as 8 tiles of 32), 512 threads / 8 waves; wave w owns
// dt slice w (16 d's) for all 3 matrices. The 24 weight fragments are hoisted
// into registers ONCE per block (8x less weight L2 traffic); x staging is
// double-buffered in LDS so tile t+1's loads overlap tile t's MFMA+epilogue.
__global__ __launch_bounds__(512, 1) void qkv_kernel(
    const float* __restrict__ x,
    const ushort* __restrict__ Wh, const ushort* __restrict__ Wl,
    const float* __restrict__ bq, const float* __restrict__ bk,
    const float* __restrict__ bv,
    ushort* __restrict__ sqT, ushort* __restrict__ ekTF, ushort* __restrict__ ekvTF,
    float* __restrict__ Pk, float* __restrict__ Pkv)
{
    __shared__ ushort Ah[2][32 * 128];   // frag order: ((lt*4+ks)*64+lane)*8+j
    __shared__ ushort Al[2][32 * 128];
    const int n = blockIdx.y, bx = blockIdx.x;
    const int tid = threadIdx.x;
    const int wave = tid >> 6;        // = dt slice 0..7
    const int lane = tid & 63;

    // Pad-tile zeroing: bx 1..7 zero slot bx; bx 0 zeros slots 0, 8, 9.
    {
        const int nrep = (bx == 0) ? 3 : 1;
        for (int s = 0; s < nrep; ++s) {
            const int slot = (s == 0) ? bx : (7 + s);
            const int jt_p = (slot < PADF) ? slot : (NT + slot);
            const size_t zb = ((size_t)n * NTP + jt_p) * 2048 + (size_t)tid * 4;
            ushort4 z; z.x = 0; z.y = 0; z.z = 0; z.w = 0;
            *(ushort4*)&ekTF [zb] = z;
            *(ushort4*)&ekvTF[zb] = z;
        }
    }

    // ---- hoist ALL weight fragments for this wave's dt slice (24 frags) ----
    const bf16x8* WhV = (const bf16x8*)Wh;
    const bf16x8* WlV = (const bf16x8*)Wl;
    bf16x8 wfh[4][3], wfl[4][3];
    #pragma unroll
    for (int ks = 0; ks < 4; ++ks)
        #pragma unroll
        for (int m = 0; m < 3; ++m) {
            const int fi = ((m * 8 + wave) * 4 + ks) * 64 + lane;
            wfh[ks][m] = WhV[fi];
            wfl[ks][m] = WlV[fi];
        }

    const int lo = tid & 31;          // l within tile
    const int cq = tid >> 5;          // 0..15, c0 = cq*8
    const int c0 = cq * 8;
    const int sidx = (((lo >> 4) * 4 + (cq >> 2)) * 64 + (cq & 3) * 16 + (lo & 15)) * 8;

    const int dcol = lane & 15;
    const int d = wave * 16 + dcol;
    const float b0 = bq[d], b1 = bk[d], b2 = bv[d];
    const int lrow0 = (lane >> 4) * 4;

    // ---- staging helpers ----
    auto LOADX = [&](int t, float* xv) {
        const int l = (bx * TPB + t) * 32 + lo;
        #pragma unroll
        for (int u = 0; u < 8; ++u)
            xv[u] = x[((size_t)n * DM + c0 + u) * SL + l];
    };
    auto CVTWRITE = [&](const float* xv, int b) {
        unsigned xb[8];
        #pragma unroll
        for (int u = 0; u < 8; ++u) xb[u] = __float_as_uint(xv[u]);
        unsigned hv32[4], lv32[4];
        #pragma unroll
        for (int p = 0; p < 4; ++p) {
            hv32[p] = (xb[2 * p] >> 16) | (xb[2 * p + 1] & 0xFFFF0000u);
            const float r0 = xv[2 * p]     - __uint_as_float(xb[2 * p]     & 0xFFFF0000u);
            const float r1 = xv[2 * p + 1] - __uint_as_float(xb[2 * p + 1] & 0xFFFF0000u);
            lv32[p] = pk_bf16(r0, r1);
        }
        *(uint4*)&Ah[b][sidx] = make_uint4(hv32[0], hv32[1], hv32[2], hv32[3]);
        *(uint4*)&Al[b][sidx] = make_uint4(lv32[0], lv32[1], lv32[2], lv32[3]);
    };

    // ---- prologue: stage tile 0 ----
    {
        float xv[8];
        LOADX(0, xv);
        CVTWRITE(xv, 0);
    }
    __syncthreads();

    float psk = 0.f, pskv = 0.f;
    #pragma unroll
    for (int t = 0; t < TPB; ++t) {
        const int bsel = t & 1;
        float xn[8];
        if (t + 1 < TPB) LOADX(t + 1, xn);   // issue early; hides under MFMA

        // ---- MFMA on buf bsel ----
        f32x4 acc[3][2];
        #pragma unroll
        for (int lt = 0; lt < 2; ++lt) {
            acc[0][lt] = (f32x4){b0, b0, b0, b0};
            acc[1][lt] = (f32x4){b1, b1, b1, b1};
            acc[2][lt] = (f32x4){b2, b2, b2, b2};
        }
        #pragma unroll
        for (int ks = 0; ks < 4; ++ks) {
            #pragma unroll
            for (int lt = 0; lt < 2; ++lt) {
                const bf16x8 ah = *(const bf16x8*)&Ah[bsel][((lt * 4 + ks) * 64 + lane) * 8];
                const bf16x8 al = *(const bf16x8*)&Al[bsel][((lt * 4 + ks) * 64 + lane) * 8];
                #pragma unroll
                for (int m = 0; m < 3; ++m) {
                    acc[m][lt] = __builtin_amdgcn_mfma_f32_16x16x32_bf16(
                        ah, wfh[ks][m], acc[m][lt], 0, 0, 0);
                    acc[m][lt] = __builtin_amdgcn_mfma_f32_16x16x32_bf16(
                        al, wfh[ks][m], acc[m][lt], 0, 0, 0);
                    acc[m][lt] = __builtin_amdgcn_mfma_f32_16x16x32_bf16(
                        ah, wfl[ks][m], acc[m][lt], 0, 0, 0);
                }
            }
        }

        // ---- epilogue for tile t ----
        const int gt = bx * TPB + t;
        #pragma unroll
        for (int lt = 0; lt < 2; ++lt) {
            const f32x4 q4 = acc[0][lt];
            const f32x4 k4 = acc[1][lt];
            const f32x4 v4 = acc[2][lt];
            float e[4], z[4];
            unsigned su[4];
            #pragma unroll
            for (int r = 0; r < 4; ++r) {
                e[r] = __expf(k4[r]);
                z[r] = e[r] * v4[r];
                const float s = fminf(__builtin_amdgcn_rcpf(1.f + __expf(-q4[r])), 1.f);
                su[r] = (unsigned)(s * 65535.f + 0.5f);
                psk  += e[r];
                pskv += z[r];
            }
            const int jt = gt * 2 + lt;
            const size_t tb = ((size_t)n * NTP + PADF + jt) * 2048
                            + (size_t)d * 16 + lrow0;
            const size_t sb = ((size_t)n * NT + jt) * 2048
                            + (size_t)d * 16 + lrow0;
            *(uint2*)&ekTF [tb] = make_uint2(pk_bf16(e[0], e[1]), pk_bf16(e[2], e[3]));
            *(uint2*)&ekvTF[tb] = make_uint2(pk_bf16(z[0], z[1]), pk_bf16(z[2], z[3]));
            *(uint2*)&sqT  [sb] = make_uint2(su[0] | (su[1] << 16), su[2] | (su[3] << 16));
        }

        // ---- stage tile t+1 into the other buffer ----
        if (t + 1 < TPB) CVTWRITE(xn, bsel ^ 1);
        __syncthreads();
    }

    {
        float a = psk, b = pskv;
        a += __shfl_xor(a, 16, 64); a += __shfl_xor(a, 32, 64);
        b += __shfl_xor(b, 16, 64); b += __shfl_xor(b, 32, 64);
        if (lane < 16) {
            const size_t o = ((size_t)n * QBX + bx) * DM + d;
            Pk [o] = a;
            Pkv[o] = b;
        }
    }
}

// FUSED band correction + output projection, wave-local handoff.
__global__ __launch_bounds__(256, 4) void band_out_kernel(
    const ushort* __restrict__ ekTF, const ushort* __restrict__ ekvTF,
    const ushort* __restrict__ WB,
    const float* __restrict__ Pk, const float* __restrict__ Pkv,
    const ushort* __restrict__ sqT,
    const ushort* __restrict__ Wh, const ushort* __restrict__ Wl,
    const float* __restrict__ bo, float* __restrict__ out)
{
    __shared__ __align__(16) union {
        float ylds[64 * YST];   // y fp32, [row l_local][col d]
        float ot[128 * OST];    // out transpose buffer [c][l_local]
        float red[8][DM];       // Pk-reduction scratch (used before ylds)
    } u;
    __shared__ float SkL[DM], SkvL[DM];

    const int bid = blockIdx.x;          // 0..1023
    const int xcd = bid & 7;
    const int slot = bid >> 3;           // 0..127
    const int nsub = slot >> 5;          // 0..3
    const int itg  = slot & 31;          // 0..31
    const int n = xcd * 4 + nsub;        // 4 n's per XCD
    const int wave = threadIdx.x >> 6;
    const int lane = threadIdx.x & 63;
    const int it = itg * 4 + wave;       // 0..127
    const int l0 = itg * 64;

    const int dcol = lane & 15;
    const int jgrp8 = (lane >> 4) << 3;

    // Hoist all 5 WB A-fragments (hides L2 latency under the Pk reduction).
    const bf16x8* WBv = (const bf16x8*)(WB + (size_t)it * 2560);
    bf16x8 aWB[5];
    #pragma unroll
    for (int ks = 0; ks < 5; ++ks) aWB[ks] = WBv[ks * 64 + lane];

    // ---- Reduce Pk/Pkv (QBX segs) -> SkL/SkvL via float4 + LDS tree ----
    {
        const int tid = threadIdx.x;
        const int q = tid & 31;          // d-quad 0..31
        const int g = tid >> 5;          // 0..7: g<4 -> Sk segs, g>=4 -> Skv
        const float* P = (g < 4) ? Pk : Pkv;
        const int s0 = (g & 3) * (QBX / 4);
        f32x4 a4 = (f32x4){0.f, 0.f, 0.f, 0.f};
        #pragma unroll
        for (int s = 0; s < QBX / 4; ++s) {
            const f32x4 v = *(const f32x4*)&P[((size_t)n * QBX + s0 + s) * DM + q * 4];
            a4 += v;
        }
        *(f32x4*)&u.red[g][q * 4] = a4;
    }
    __syncthreads();
    {
        const int tid = threadIdx.x;
        if (tid < 128)
            SkL[tid]  = u.red[0][tid] + u.red[1][tid] + u.red[2][tid] + u.red[3][tid];
        else {
            const int dd = tid - 128;
            SkvL[dd] = u.red[4][dd] + u.red[5][dd] + u.red[6][dd] + u.red[7][dd];
        }
    }
    __syncthreads();

    // ---- Phase 1: banded MFMA, dt-outer; gate + ylds write fused per dt ----
    // lane-dependent tile select: jt_p = it + 2ks + (lane>>5); jo = ((lane>>4)&1)*8
    const size_t lsel = (size_t)(lane >> 5) * 2048 + (size_t)((lane >> 4) & 1) * 8
                      + (size_t)dcol * 16;
    size_t tb[5];
    #pragma unroll
    for (int ks = 0; ks < 5; ++ks)
        tb[ks] = ((size_t)n * NTP + it + 2 * ks) * 2048 + lsel;

    const int irow0 = (lane >> 4) << 2;
    const size_t sgb = ((size_t)n * NT + it) * 2048 + irow0;

    #pragma unroll
    for (int dt = 0; dt < 8; ++dt) {
        const int d = dt * 16 + dcol;
        const float sk = SkL[d];
        const float sv = SkvL[d];
        f32x4 den = (f32x4){sk, sk, sk, sk};
        f32x4 num = (f32x4){sv, sv, sv, sv};
        #pragma unroll
        for (int ks = 0; ks < 5; ++ks) {
            const size_t rbase = tb[ks] + (size_t)dt * 256;   // dt*16 rows * 16 jo
            const bf16x8 bden = *(const bf16x8*)(ekTF  + rbase);
            const bf16x8 bnum = *(const bf16x8*)(ekvTF + rbase);
            den = __builtin_amdgcn_mfma_f32_16x16x32_bf16(aWB[ks], bden, den, 0, 0, 0);
            num = __builtin_amdgcn_mfma_f32_16x16x32_bf16(aWB[ks], bnum, num, 0, 0, 0);
        }
        // Gate with sigmoid(q) (unorm16 tiled); write y slice to LDS stripe.
        const ushort4 s4 = *(const ushort4*)&sqT[sgb + (size_t)d * 16];
        float sf[4];
        sf[0] = (float)s4.x; sf[1] = (float)s4.y;
        sf[2] = (float)s4.z; sf[3] = (float)s4.w;
        #pragma unroll
        for (int r = 0; r < 4; ++r) {
            const float s = sf[r] * (1.f / 65535.f);
            const float y = s * num[r] * __builtin_amdgcn_rcpf(den[r]);
            u.ylds[(wave * 16 + irow0 + r) * YST + d] = y;
        }
    }

    // ---- Handoff: read own stripe in A-octet order, convert via HW cvt ----
    bf16x8 yh[4], yl[4];
    {
        const int arow = wave * 16 + (lane & 15);
        #pragma unroll
        for (int ks = 0; ks < 4; ++ks) {
            const int base = arow * YST + ks * 32 + jgrp8;
            const float4 a0 = *(const float4*)&u.ylds[base];
            const float4 a1 = *(const float4*)&u.ylds[base + 4];
            float af[8];
            af[0] = a0.x; af[1] = a0.y; af[2] = a0.z; af[3] = a0.w;
            af[4] = a1.x; af[5] = a1.y; af[6] = a1.z; af[7] = a1.w;
            unsigned ab[8];
            #pragma unroll
            for (int t = 0; t < 8; ++t) ab[t] = __float_as_uint(af[t]);
            unsigned hw[4], lw[4];
            #pragma unroll
            for (int p = 0; p < 4; ++p) {
                hw[p] = (ab[2 * p] >> 16) | (ab[2 * p + 1] & 0xFFFF0000u);
                const float r0 = af[2 * p]     - __uint_as_float(ab[2 * p]     & 0xFFFF0000u);
                const float r1 = af[2 * p + 1] - __uint_as_float(ab[2 * p + 1] & 0xFFFF0000u);
                lw[p] = pk_bf16(r0, r1);
            }
            union { u32x4 w; bf16x8 b; } ch, cl;
            ch.w = (u32x4){hw[0], hw[1], hw[2], hw[3]};
            cl.w = (u32x4){lw[0], lw[1], lw[2], lw[3]};
            yh[ks] = ch.b;
            yl[ks] = cl.b;
        }
    }
    __syncthreads();   // all waves done with ylds; ot may now overwrite

    // ---- Phase 2: out projection, ct-outer (one acc live at a time) ----
    const bf16x8* WhV = (const bf16x8*)Wh;
    const bf16x8* WlV = (const bf16x8*)Wl;
    #pragma unroll
    for (int ct = 0; ct < 8; ++ct) {
        const float b0 = bo[ct * 16 + dcol];
        f32x4 acc = (f32x4){b0, b0, b0, b0};
        #pragma unroll
        for (int ks = 0; ks < 4; ++ks) {
            const int fi = ((24 + ct) * 4 + ks) * 64 + lane;  // mat=3 (Wo)
            const bf16x8 bh = WhV[fi];
            const bf16x8 bl = WlV[fi];
            acc = __builtin_amdgcn_mfma_f32_16x16x32_bf16(yh[ks], bh, acc, 0, 0, 0);
            acc = __builtin_amdgcn_mfma_f32_16x16x32_bf16(yl[ks], bh, acc, 0, 0, 0);
            acc = __builtin_amdgcn_mfma_f32_16x16x32_bf16(yh[ks], bl, acc, 0, 0, 0);
        }
        // Transpose through LDS: ot[c][l_local]; C rows = wave's 16 l's.
        const int c = ct * 16 + dcol;
        #pragma unroll
        for (int r = 0; r < 4; ++r)
            u.ot[c * OST + wave * 16 + irow0 + r] = acc[r];
    }
    __syncthreads();

    // Coalesced float4 store: 64 contiguous floats per c row, 8 reps.
    const int tid = threadIdx.x;
    #pragma unroll
    for (int rep = 0; rep < 8; ++rep) {
        const int e = rep * 256 + tid;   // 0..2047
        const int c = e >> 4;            // 0..127
        const int lq = e & 15;           // 0..15 -> 4-float chunk
        const float4 v = *(const float4*)&u.ot[c * OST + lq * 4];
        *(float4*)&out[((size_t)n * DM + c) * SL + l0 + lq * 4] = v;
    }
}

extern "C" void kernel_launch(void* const* d_in, const int* in_sizes, int n_in,
                              void* d_out, int out_size, void* d_ws, size_t ws_size,
                              hipStream_t stream)
{
    const float* x        = (const float*)d_in[0];
    const float* Wq       = (const float*)d_in[1];
    const float* bq       = (const float*)d_in[2];
    const float* Wk       = (const float*)d_in[3];
    const float* bk       = (const float*)d_in[4];
    const float* Wv       = (const float*)d_in[5];
    const float* bv       = (const float*)d_in[6];
    const float* Wo       = (const float*)d_in[7];
    const float* bo       = (const float*)d_in[8];
    const float* pos_bias = (const float*)d_in[9];
    float* out = (float*)d_out;

    ushort* sqT   = (ushort*)d_ws;                       // NB*NT*2048 ushorts
    ushort* ekTF  = sqT   + (size_t)NB * NT * 2048;
    ushort* ekvTF = ekTF  + (size_t)NB * NTP * 2048;
    ushort* WB    = ekvTF + (size_t)NB * NTP * 2048;
    float*  Pk    = (float*)(WB + (size_t)128 * 2560);
    float*  Pkv   = Pk   + (size_t)NB * QBX * DM;
    ushort* Wh    = (ushort*)(Pkv + (size_t)NB * QBX * DM);
    ushort* Wl    = Wh + (size_t)4 * DM * DM;

    setup_kernel   <<<dim3(384),     512, 0, stream>>>(Wq, Wk, Wv, Wo, pos_bias,
                                                       Wh, Wl, WB);
    qkv_kernel     <<<dim3(QBX, NB), 512, 0, stream>>>(x, Wh, Wl, bq, bk, bv,
                                                       sqT, ekTF, ekvTF, Pk, Pkv);
    band_out_kernel<<<dim3(NB * 32), 256, 0, stream>>>(ekTF, ekvTF, WB, Pk, Pkv, sqT,
                                                       Wh, Wl, bo, out);
}